// Round 5
// baseline (482.774 us; speedup 1.0000x reference)
//
#include <hip/hip_runtime.h>

// VoxelEncoding via counting-sort by voxel id.
// Measured-primitive composition (r0-r4 evidence):
//   - returning far-atomics: ~64 B/op memory-side RMW, op-rate bound -> pay
//     this ONCE (k_hist_rank, ILP x8).
//   - scattered payload writes (>=16 B over 40 MB): ~4x line amplification,
//     no L2 merge (r0: 192 MB WRITE, 165 us) -> NEVER scatter payload.
//   - scattered 4-B writes into an 8-MB (1 MB/XCD-L2) array: line-merge in
//     L2, cheap (r1/r2) -> scatter ONLY {ord, vsort}, 4 B each.
//   - random READS + seq writes: cheap (r2 k_gather below top-5) -> payload
//     moves via gather, in the read direction.
// Pipeline:
//   K0 zero hist -> K1 hist+rank (only atomic pass, 8 pts/thread)
//   -> K2 block scan -> K3 scan block sums (bsums add folded into K5)
//   -> K5 place_ord: pos = hist[v]+bsums[v>>10]+rank[i];
//      scatter ord[pos]=i, vsort[pos]=v (two 4-B L2-merging scatters)
//   -> K5b gather: seq ord -> random pts reads (L3-hot) -> seq rec writes
//   -> K6 main (unchanged, 127 us @ FETCH 278 MB ~ transaction-rate limit
//      of the 4M-corner emb gather): seq vsort/rec; same-voxel adjacency
//      merges emb reads in TA/L1; out = one full 64-B line per point (NT).

typedef float v4f __attribute__((ext_vector_type(4)));

// ---------------- K0: zero histogram ----------------
__global__ void k_zero(unsigned* __restrict__ hist, int n) {
    int i = blockIdx.x * blockDim.x + threadIdx.x;
    if (i < n) hist[i] = 0u;
}

// ---------------- K1: histogram + per-point rank, 8 pts/thread ----------------
__global__ __launch_bounds__(256) void k_hist_rank(const int* __restrict__ p2v,
                                                   unsigned* __restrict__ hist,
                                                   unsigned* __restrict__ rank, int N) {
    const int base = (blockIdx.x * blockDim.x + threadIdx.x) * 8;
    if (base + 7 < N) {
        const int4 a = *(const int4*)(p2v + base);
        const int4 b = *(const int4*)(p2v + base + 4);
        const unsigned r0 = atomicAdd(&hist[a.x], 1u);
        const unsigned r1 = atomicAdd(&hist[a.y], 1u);
        const unsigned r2 = atomicAdd(&hist[a.z], 1u);
        const unsigned r3 = atomicAdd(&hist[a.w], 1u);
        const unsigned r4 = atomicAdd(&hist[b.x], 1u);
        const unsigned r5 = atomicAdd(&hist[b.y], 1u);
        const unsigned r6 = atomicAdd(&hist[b.z], 1u);
        const unsigned r7 = atomicAdd(&hist[b.w], 1u);
        uint4 o0; o0.x = r0; o0.y = r1; o0.z = r2; o0.w = r3;
        uint4 o1; o1.x = r4; o1.y = r5; o1.z = r6; o1.w = r7;
        *(uint4*)(rank + base)     = o0;
        *(uint4*)(rank + base + 4) = o1;
    } else {
        for (int k = 0; k < 8; ++k)
            if (base + k < N) rank[base + k] = atomicAdd(&hist[p2v[base + k]], 1u);
    }
}

// ---------------- K2: per-block exclusive scan (1024 bins/block) ----------------
__global__ __launch_bounds__(256) void k_scan_blocks(unsigned* __restrict__ hist,
                                                     unsigned* __restrict__ bsums, int nbins) {
    __shared__ unsigned tsum[256];
    const int tid = threadIdx.x;
    const int i0 = blockIdx.x * 1024 + tid * 4;
    unsigned v[4]; unsigned s = 0;
    #pragma unroll
    for (int k = 0; k < 4; ++k) {
        unsigned c = (i0 + k < nbins) ? hist[i0 + k] : 0u;
        v[k] = s; s += c;
    }
    tsum[tid] = s; __syncthreads();
    for (int off = 1; off < 256; off <<= 1) {
        unsigned x = tsum[tid];
        unsigned y = (tid >= off) ? tsum[tid - off] : 0u;
        __syncthreads();
        tsum[tid] = x + y;
        __syncthreads();
    }
    unsigned prefix = (tid > 0) ? tsum[tid - 1] : 0u;
    #pragma unroll
    for (int k = 0; k < 4; ++k) {
        if (i0 + k < nbins) hist[i0 + k] = prefix + v[k];
    }
    if (tid == 255) bsums[blockIdx.x] = tsum[255];
}

// ---------------- K3: exclusive scan of block sums (single block, nb <= 1024) ----------------
__global__ __launch_bounds__(256) void k_scan_sums(unsigned* __restrict__ bsums, int nb) {
    __shared__ unsigned tsum[256];
    const int tid = threadIdx.x;
    const int i0 = tid * 4;
    unsigned v[4]; unsigned s = 0;
    #pragma unroll
    for (int k = 0; k < 4; ++k) {
        unsigned c = (i0 + k < nb) ? bsums[i0 + k] : 0u;
        v[k] = s; s += c;
    }
    tsum[tid] = s; __syncthreads();
    for (int off = 1; off < 256; off <<= 1) {
        unsigned x = tsum[tid];
        unsigned y = (tid >= off) ? tsum[tid - off] : 0u;
        __syncthreads();
        tsum[tid] = x + y;
        __syncthreads();
    }
    unsigned prefix = (tid > 0) ? tsum[tid - 1] : 0u;
    #pragma unroll
    for (int k = 0; k < 4; ++k) {
        if (i0 + k < nb) bsums[i0 + k] = prefix + v[k];
    }
}

// ---------------- K5: scatter ONLY 4-B ord & vsort (L2-merging, no atomics) ----------------
__global__ __launch_bounds__(256) void k_place_ord(
    const int*      __restrict__ p2v,
    const unsigned* __restrict__ rank,
    const unsigned* __restrict__ hist,    // per-chunk-local exclusive prefix
    const unsigned* __restrict__ bsums,   // scanned chunk offsets (2 KB, L1-hot)
    unsigned* __restrict__ ord,
    unsigned* __restrict__ vsort,
    int N)
{
    const int base = (blockIdx.x * blockDim.x + threadIdx.x) * 4;
    if (base + 3 < N) {
        const int4  v4r = *(const int4*)(p2v + base);
        const uint4 r4  = *(const uint4*)(rank + base);
        const unsigned pos0 = hist[v4r.x] + bsums[((unsigned)v4r.x) >> 10] + r4.x;
        const unsigned pos1 = hist[v4r.y] + bsums[((unsigned)v4r.y) >> 10] + r4.y;
        const unsigned pos2 = hist[v4r.z] + bsums[((unsigned)v4r.z) >> 10] + r4.z;
        const unsigned pos3 = hist[v4r.w] + bsums[((unsigned)v4r.w) >> 10] + r4.w;
        ord[pos0] = (unsigned)(base + 0);
        ord[pos1] = (unsigned)(base + 1);
        ord[pos2] = (unsigned)(base + 2);
        ord[pos3] = (unsigned)(base + 3);
        vsort[pos0] = (unsigned)v4r.x;
        vsort[pos1] = (unsigned)v4r.y;
        vsort[pos2] = (unsigned)v4r.z;
        vsort[pos3] = (unsigned)v4r.w;
    } else {
        for (int k = 0; k < 4; ++k) {
            const int i = base + k;
            if (i >= N) break;
            const int v = p2v[i];
            const unsigned pos = hist[v] + bsums[((unsigned)v) >> 10] + rank[i];
            ord[pos] = (unsigned)i;
            vsort[pos] = (unsigned)v;
        }
    }
}

// ---------------- K5b: gather payload into sorted order (random reads, seq writes) ----------------
__global__ __launch_bounds__(256) void k_gather(
    const unsigned* __restrict__ ord,
    const float*    __restrict__ pts,
    v4f*            __restrict__ rec,
    int N)
{
    int n = blockIdx.x * blockDim.x + threadIdx.x;
    if (n >= N) return;
    const int orig = (int)ord[n];
    v4f r;
    r.x = pts[3 * (size_t)orig + 0];
    r.y = pts[3 * (size_t)orig + 1];
    r.z = pts[3 * (size_t)orig + 2];
    r.w = __int_as_float(orig);
    rec[n] = r;
}

// ---------------- K6: main interpolation over sorted points ----------------
__global__ __launch_bounds__(256) void k_main(
    const unsigned* __restrict__ vsort, const v4f* __restrict__ rec,
    const float* __restrict__ emb,   // (N_EMB,16)
    const float* __restrict__ cp,    // (N_VOX,3)
    const int*   __restrict__ c2c,   // (N_VOX,8)
    const float* __restrict__ vox,
    float*       __restrict__ out,   // (N,16)
    int N)
{
    const int t = blockIdx.x * blockDim.x + threadIdx.x;
    const int n = t >> 2;        // sorted point index
    const int q = t & 3;         // 4-dim chunk
    if (n >= N) return;

    const unsigned v = vsort[n];
    const v4f r = rec[n];
    const int orig = __float_as_int(r.w);

    const int4* c4 = (const int4*)(c2c + 8 * (size_t)v);
    const int4 ci0 = c4[0];
    const int4 ci1 = c4[1];
    const int cidx[8] = {ci0.x, ci0.y, ci0.z, ci0.w, ci1.x, ci1.y, ci1.z, ci1.w};

    v4f e[8];
    #pragma unroll
    for (int c = 0; c < 8; ++c) {
        e[c] = *(const v4f*)(emb + 16 * (size_t)cidx[c] + 4 * q);
    }

    const float inv_vs = 1.0f / vox[0];
    const float* cpp = cp + 3 * (size_t)v;
    const float px = (r.x - cpp[0]) * inv_vs + 0.5f;
    const float py = (r.y - cpp[1]) * inv_vs + 0.5f;
    const float pz = (r.z - cpp[2]) * inv_vs + 0.5f;
    const float wx[2] = {1.0f - px, px};
    const float wy[2] = {1.0f - py, py};
    const float wz[2] = {1.0f - pz, pz};

    v4f acc = (v4f)(0.0f);
    #pragma unroll
    for (int c = 0; c < 8; ++c) {
        const float w = wx[(c >> 2) & 1] * wy[(c >> 1) & 1] * wz[c & 1];
        acc.x = fmaf(w, e[c].x, acc.x);
        acc.y = fmaf(w, e[c].y, acc.y);
        acc.z = fmaf(w, e[c].z, acc.z);
        acc.w = fmaf(w, e[c].w, acc.w);
    }

    __builtin_nontemporal_store(acc, (v4f*)(out + 16 * (size_t)orig + 4 * q));
}

// ---------------- fallback (no-sort direct), used only if ws too small ----------------
__global__ __launch_bounds__(256) void k_direct(
    const float* __restrict__ pts, const int* __restrict__ p2v,
    const float* __restrict__ emb, const float* __restrict__ cp,
    const int* __restrict__ c2c, const float* __restrict__ vox,
    float* __restrict__ out, int N)
{
    const int t = blockIdx.x * blockDim.x + threadIdx.x;
    const int n = t >> 2, q = t & 3;
    if (n >= N) return;
    const int v = p2v[n];
    const int4* c4 = (const int4*)(c2c + 8 * (size_t)v);
    const int4 ci0 = c4[0], ci1 = c4[1];
    const int cidx[8] = {ci0.x, ci0.y, ci0.z, ci0.w, ci1.x, ci1.y, ci1.z, ci1.w};
    v4f e[8];
    #pragma unroll
    for (int c = 0; c < 8; ++c) e[c] = *(const v4f*)(emb + 16 * (size_t)cidx[c] + 4 * q);
    const float inv_vs = 1.0f / vox[0];
    const float* pp = pts + 3 * (size_t)n;
    const float* cpp = cp + 3 * (size_t)v;
    const float px = (pp[0] - cpp[0]) * inv_vs + 0.5f;
    const float py = (pp[1] - cpp[1]) * inv_vs + 0.5f;
    const float pz = (pp[2] - cpp[2]) * inv_vs + 0.5f;
    const float wx[2] = {1.0f - px, px};
    const float wy[2] = {1.0f - py, py};
    const float wz[2] = {1.0f - pz, pz};
    v4f acc = (v4f)(0.0f);
    #pragma unroll
    for (int c = 0; c < 8; ++c) {
        const float w = wx[(c >> 2) & 1] * wy[(c >> 1) & 1] * wz[c & 1];
        acc.x = fmaf(w, e[c].x, acc.x); acc.y = fmaf(w, e[c].y, acc.y);
        acc.z = fmaf(w, e[c].z, acc.z); acc.w = fmaf(w, e[c].w, acc.w);
    }
    __builtin_nontemporal_store(acc, (v4f*)(out + 4 * (size_t)t));
}

extern "C" void kernel_launch(void* const* d_in, const int* in_sizes, int n_in,
                              void* d_out, int out_size, void* d_ws, size_t ws_size,
                              hipStream_t stream) {
    const float* pts = (const float*)d_in[0];
    const int*   p2v = (const int*)d_in[1];
    const float* emb = (const float*)d_in[2];
    const float* cp  = (const float*)d_in[3];
    const int*   c2c = (const int*)d_in[4];
    const float* vox = (const float*)d_in[5];
    float*       out = (float*)d_out;

    const int N  = in_sizes[1];       // 2,000,000 points
    const int NV = in_sizes[4] / 8;   // 500,000 voxels

    // workspace layout (bytes)
    const size_t off_hist  = 0;                        // NV * 4   (2 MB)
    const size_t off_bsums = 2u * 1024u * 1024u;       // <=1024 * 4
    const size_t off_rank  = 4u * 1024u * 1024u;       // N * 4    (8 MB)
    const size_t off_ord   = 12u * 1024u * 1024u;      // N * 4    (8 MB)
    const size_t off_vsort = 20u * 1024u * 1024u;      // N * 4    (8 MB)
    const size_t off_rec   = 28u * 1024u * 1024u;      // N * 16   (32 MB)
    const size_t need = off_rec + (size_t)N * 16u;

    if (ws_size < need) {
        const int block = 256;
        const long long threads = 4LL * N;
        k_direct<<<(int)((threads + block - 1) / block), block, 0, stream>>>(
            pts, p2v, emb, cp, c2c, vox, out, N);
        return;
    }

    unsigned* hist  = (unsigned*)((char*)d_ws + off_hist);
    unsigned* bsums = (unsigned*)((char*)d_ws + off_bsums);
    unsigned* rank  = (unsigned*)((char*)d_ws + off_rank);
    unsigned* ord   = (unsigned*)((char*)d_ws + off_ord);
    unsigned* vsort = (unsigned*)((char*)d_ws + off_vsort);
    v4f*      rec   = (v4f*)((char*)d_ws + off_rec);

    const int block = 256;
    const int nscan = (NV + 1023) / 1024;   // 489 blocks; k_scan_sums handles <=1024

    k_zero<<<(NV + block - 1) / block, block, 0, stream>>>(hist, NV);
    k_hist_rank<<<(N + block * 8 - 1) / (block * 8), block, 0, stream>>>(p2v, hist, rank, N);
    k_scan_blocks<<<nscan, 256, 0, stream>>>(hist, bsums, NV);
    k_scan_sums<<<1, 256, 0, stream>>>(bsums, nscan);
    k_place_ord<<<(N + block * 4 - 1) / (block * 4), block, 0, stream>>>(
        p2v, rank, hist, bsums, ord, vsort, N);
    k_gather<<<(N + block - 1) / block, block, 0, stream>>>(ord, pts, rec, N);

    const long long threads = 4LL * N;
    k_main<<<(int)((threads + block - 1) / block), block, 0, stream>>>(
        vsort, rec, emb, cp, c2c, vox, out, N);
}

// Round 6
// 477.388 us; speedup vs baseline: 1.0113x; 1.0113x over previous
//
#include <hip/hip_runtime.h>

// VoxelEncoding via counting-sort by voxel id — XCD-local atomics version.
//
// Measured r0-r5:
//   - device-scope returning atomicAdd: ~64 B/op WRITE_SIZE at ~800 GB/s
//     => ~12 Gop/s op-rate wall (RMW at the cross-XCD coherence point).
//     ILP x8 changed nothing (r3->r4) -> throughput-bound, not latency.
//   - scattered payload writes are ~4x amplified but k_place(r4) beat the
//     place_ord+gather split (r5: +24 us) -> keep direct payload scatter.
//   - k_main: 127 us @ FETCH 278 MB (structural: 500K voxels x 8 corners
//     x 64-B emb lines, random corners -> no L2 reuse) — near gather limit.
//
// Fix this round: atomics execute where their SCOPE requires. Workgroup
// scope -> no SC1 -> RMW in the LOCAL XCD's TCC (L2), atomic for all CUs
// of that XCD, 2-MB copy L2-resident. Structure provides cross-XCD safety:
// 8 private hist copies (disjoint 2-MB regions, no shared lines), selected
// by s_getreg(HW_REG_XCC_ID); rank packs the xcd id in bits 28..30.
// Scan sums the 8 copies and writes base[x][v] (in place) so that
//   pos = base[x][v] + bsums[v>>10] + r   is a global bijection with
// same-voxel adjacency. Kernel-boundary release flushes L2 -> scan sees
// all copies.
//
//   K0 zero 8xNV -> K1 hist+rank (xcd-local atomics, 8 pts/thread)
//   -> K2 scan (8-copy sum + per-xcd base, in place) -> K3 scan block sums
//   -> K5 place (r4 structure: 4 pts/thread, payload scatter, no atomics)
//   -> K6 main (unchanged, proven)

typedef float v4f __attribute__((ext_vector_type(4)));
#define NXCD 8

// ---------------- K0: zero the 8 histogram copies ----------------
__global__ void k_zero(unsigned* __restrict__ hist, int n) {
    int i = blockIdx.x * blockDim.x + threadIdx.x;
    if (i < n) hist[i] = 0u;
}

// ---------------- K1: histogram + rank via XCD-local atomics, 8 pts/thread ----------------
__global__ __launch_bounds__(256) void k_hist_rank(const int* __restrict__ p2v,
                                                   unsigned* __restrict__ hist,
                                                   unsigned* __restrict__ rank,
                                                   int N, int NV) {
    unsigned xcc;
    asm volatile("s_getreg_b32 %0, hwreg(HW_REG_XCC_ID)" : "=s"(xcc));
    xcc &= (NXCD - 1);
    unsigned* __restrict__ hx = hist + (size_t)xcc * (size_t)NV;
    const unsigned xtag = xcc << 28;

    const int base = (blockIdx.x * blockDim.x + threadIdx.x) * 8;
    if (base + 7 < N) {
        const int4 a = *(const int4*)(p2v + base);
        const int4 b = *(const int4*)(p2v + base + 4);
        // 8 independent XCD-local (TCC) fetch-adds in flight
        const unsigned r0 = __hip_atomic_fetch_add(&hx[a.x], 1u, __ATOMIC_RELAXED, __HIP_MEMORY_SCOPE_WORKGROUP);
        const unsigned r1 = __hip_atomic_fetch_add(&hx[a.y], 1u, __ATOMIC_RELAXED, __HIP_MEMORY_SCOPE_WORKGROUP);
        const unsigned r2 = __hip_atomic_fetch_add(&hx[a.z], 1u, __ATOMIC_RELAXED, __HIP_MEMORY_SCOPE_WORKGROUP);
        const unsigned r3 = __hip_atomic_fetch_add(&hx[a.w], 1u, __ATOMIC_RELAXED, __HIP_MEMORY_SCOPE_WORKGROUP);
        const unsigned r4 = __hip_atomic_fetch_add(&hx[b.x], 1u, __ATOMIC_RELAXED, __HIP_MEMORY_SCOPE_WORKGROUP);
        const unsigned r5 = __hip_atomic_fetch_add(&hx[b.y], 1u, __ATOMIC_RELAXED, __HIP_MEMORY_SCOPE_WORKGROUP);
        const unsigned r6 = __hip_atomic_fetch_add(&hx[b.z], 1u, __ATOMIC_RELAXED, __HIP_MEMORY_SCOPE_WORKGROUP);
        const unsigned r7 = __hip_atomic_fetch_add(&hx[b.w], 1u, __ATOMIC_RELAXED, __HIP_MEMORY_SCOPE_WORKGROUP);
        uint4 o0; o0.x = r0 | xtag; o0.y = r1 | xtag; o0.z = r2 | xtag; o0.w = r3 | xtag;
        uint4 o1; o1.x = r4 | xtag; o1.y = r5 | xtag; o1.z = r6 | xtag; o1.w = r7 | xtag;
        *(uint4*)(rank + base)     = o0;
        *(uint4*)(rank + base + 4) = o1;
    } else {
        for (int k = 0; k < 8; ++k)
            if (base + k < N)
                rank[base + k] = xtag | __hip_atomic_fetch_add(&hx[p2v[base + k]], 1u,
                                        __ATOMIC_RELAXED, __HIP_MEMORY_SCOPE_WORKGROUP);
    }
}

// ---------------- K2: per-block scan over bin TOTALS + per-XCD base (in place) ----------------
// hist layout [NXCD][nbins]. On exit: hist[x][i] = (block-local exclusive
// prefix of totals at bin i) + sum_{x'<x} count[x'][i].  Add bsums[i>>10]
// (scanned in K3) to get the global base.
__global__ __launch_bounds__(256) void k_scan_blocks(unsigned* __restrict__ hist,
                                                     unsigned* __restrict__ bsums, int nbins) {
    __shared__ unsigned tsum[256];
    const int tid = threadIdx.x;
    const int i0 = blockIdx.x * 1024 + tid * 4;
    const bool full = (i0 + 3 < nbins);

    unsigned h[NXCD][4];
    #pragma unroll
    for (int x = 0; x < NXCD; ++x) {
        const unsigned* hp = hist + (size_t)x * (size_t)nbins;
        if (full) {
            const uint4 t = *(const uint4*)(hp + i0);
            h[x][0] = t.x; h[x][1] = t.y; h[x][2] = t.z; h[x][3] = t.w;
        } else {
            #pragma unroll
            for (int k = 0; k < 4; ++k) h[x][k] = (i0 + k < nbins) ? hp[i0 + k] : 0u;
        }
    }

    unsigned vloc[4]; unsigned s = 0;
    #pragma unroll
    for (int k = 0; k < 4; ++k) {
        unsigned t = 0;
        #pragma unroll
        for (int x = 0; x < NXCD; ++x) t += h[x][k];
        vloc[k] = s; s += t;
    }
    tsum[tid] = s; __syncthreads();
    for (int off = 1; off < 256; off <<= 1) {
        unsigned x = tsum[tid];
        unsigned y = (tid >= off) ? tsum[tid - off] : 0u;
        __syncthreads();
        tsum[tid] = x + y;
        __syncthreads();
    }
    const unsigned prefix = (tid > 0) ? tsum[tid - 1] : 0u;

    unsigned basev[NXCD][4];
    #pragma unroll
    for (int k = 0; k < 4; ++k) {
        unsigned b = prefix + vloc[k];
        #pragma unroll
        for (int x = 0; x < NXCD; ++x) { basev[x][k] = b; b += h[x][k]; }
    }
    #pragma unroll
    for (int x = 0; x < NXCD; ++x) {
        unsigned* hp = hist + (size_t)x * (size_t)nbins;
        if (full) {
            uint4 o; o.x = basev[x][0]; o.y = basev[x][1]; o.z = basev[x][2]; o.w = basev[x][3];
            *(uint4*)(hp + i0) = o;
        } else {
            #pragma unroll
            for (int k = 0; k < 4; ++k) if (i0 + k < nbins) hp[i0 + k] = basev[x][k];
        }
    }
    if (tid == 255) bsums[blockIdx.x] = tsum[255];
}

// ---------------- K3: exclusive scan of block sums (single block, nb <= 1024) ----------------
__global__ __launch_bounds__(256) void k_scan_sums(unsigned* __restrict__ bsums, int nb) {
    __shared__ unsigned tsum[256];
    const int tid = threadIdx.x;
    const int i0 = tid * 4;
    unsigned v[4]; unsigned s = 0;
    #pragma unroll
    for (int k = 0; k < 4; ++k) {
        unsigned c = (i0 + k < nb) ? bsums[i0 + k] : 0u;
        v[k] = s; s += c;
    }
    tsum[tid] = s; __syncthreads();
    for (int off = 1; off < 256; off <<= 1) {
        unsigned x = tsum[tid];
        unsigned y = (tid >= off) ? tsum[tid - off] : 0u;
        __syncthreads();
        tsum[tid] = x + y;
        __syncthreads();
    }
    unsigned prefix = (tid > 0) ? tsum[tid - 1] : 0u;
    #pragma unroll
    for (int k = 0; k < 4; ++k) {
        if (i0 + k < nb) bsums[i0 + k] = prefix + v[k];
    }
}

// ---------------- K5: place payload, 4 pts/thread, NO atomics (r4 structure) ----------------
__global__ __launch_bounds__(256) void k_place(
    const float* __restrict__ pts,
    const int*   __restrict__ p2v,
    const unsigned* __restrict__ rank,    // r | (xcd<<28)
    const unsigned* __restrict__ hist,    // base[x][v] after scan
    const unsigned* __restrict__ bsums,   // scanned chunk offsets (2 KB, L1-hot)
    unsigned* __restrict__ vsort,
    v4f*      __restrict__ rec,
    int N, int NV)
{
    const int base = (blockIdx.x * blockDim.x + threadIdx.x) * 4;
    if (base + 3 < N) {
        const int4  v4r = *(const int4*)(p2v + base);
        const uint4 r4  = *(const uint4*)(rank + base);
        const v4f* p4 = (const v4f*)pts;
        const size_t f0i = (size_t)(3 * (base >> 2));
        const v4f f0 = p4[f0i];
        const v4f f1 = p4[f0i + 1];
        const v4f f2 = p4[f0i + 2];

        const unsigned pos0 = hist[(size_t)(r4.x >> 28) * NV + (unsigned)v4r.x]
                              + bsums[((unsigned)v4r.x) >> 10] + (r4.x & 0x0FFFFFFFu);
        const unsigned pos1 = hist[(size_t)(r4.y >> 28) * NV + (unsigned)v4r.y]
                              + bsums[((unsigned)v4r.y) >> 10] + (r4.y & 0x0FFFFFFFu);
        const unsigned pos2 = hist[(size_t)(r4.z >> 28) * NV + (unsigned)v4r.z]
                              + bsums[((unsigned)v4r.z) >> 10] + (r4.z & 0x0FFFFFFFu);
        const unsigned pos3 = hist[(size_t)(r4.w >> 28) * NV + (unsigned)v4r.w]
                              + bsums[((unsigned)v4r.w) >> 10] + (r4.w & 0x0FFFFFFFu);

        vsort[pos0] = (unsigned)v4r.x;
        vsort[pos1] = (unsigned)v4r.y;
        vsort[pos2] = (unsigned)v4r.z;
        vsort[pos3] = (unsigned)v4r.w;

        v4f a;
        a.x = f0.x; a.y = f0.y; a.z = f0.z; a.w = __int_as_float(base + 0);
        rec[pos0] = a;
        a.x = f0.w; a.y = f1.x; a.z = f1.y; a.w = __int_as_float(base + 1);
        rec[pos1] = a;
        a.x = f1.z; a.y = f1.w; a.z = f2.x; a.w = __int_as_float(base + 2);
        rec[pos2] = a;
        a.x = f2.y; a.y = f2.z; a.z = f2.w; a.w = __int_as_float(base + 3);
        rec[pos3] = a;
    } else {
        for (int k = 0; k < 4; ++k) {
            const int i = base + k;
            if (i >= N) break;
            const int v = p2v[i];
            const unsigned rr = rank[i];
            const unsigned pos = hist[(size_t)(rr >> 28) * NV + (unsigned)v]
                                 + bsums[((unsigned)v) >> 10] + (rr & 0x0FFFFFFFu);
            vsort[pos] = (unsigned)v;
            v4f r;
            r.x = pts[3 * (size_t)i + 0];
            r.y = pts[3 * (size_t)i + 1];
            r.z = pts[3 * (size_t)i + 2];
            r.w = __int_as_float(i);
            rec[pos] = r;
        }
    }
}

// ---------------- K6: main interpolation over sorted points ----------------
__global__ __launch_bounds__(256) void k_main(
    const unsigned* __restrict__ vsort, const v4f* __restrict__ rec,
    const float* __restrict__ emb,   // (N_EMB,16)
    const float* __restrict__ cp,    // (N_VOX,3)
    const int*   __restrict__ c2c,   // (N_VOX,8)
    const float* __restrict__ vox,
    float*       __restrict__ out,   // (N,16)
    int N)
{
    const int t = blockIdx.x * blockDim.x + threadIdx.x;
    const int n = t >> 2;        // sorted point index
    const int q = t & 3;         // 4-dim chunk
    if (n >= N) return;

    const unsigned v = vsort[n];
    const v4f r = rec[n];
    const int orig = __float_as_int(r.w);

    const int4* c4 = (const int4*)(c2c + 8 * (size_t)v);
    const int4 ci0 = c4[0];
    const int4 ci1 = c4[1];
    const int cidx[8] = {ci0.x, ci0.y, ci0.z, ci0.w, ci1.x, ci1.y, ci1.z, ci1.w};

    v4f e[8];
    #pragma unroll
    for (int c = 0; c < 8; ++c) {
        e[c] = *(const v4f*)(emb + 16 * (size_t)cidx[c] + 4 * q);
    }

    const float inv_vs = 1.0f / vox[0];
    const float* cpp = cp + 3 * (size_t)v;
    const float px = (r.x - cpp[0]) * inv_vs + 0.5f;
    const float py = (r.y - cpp[1]) * inv_vs + 0.5f;
    const float pz = (r.z - cpp[2]) * inv_vs + 0.5f;
    const float wx[2] = {1.0f - px, px};
    const float wy[2] = {1.0f - py, py};
    const float wz[2] = {1.0f - pz, pz};

    v4f acc = (v4f)(0.0f);
    #pragma unroll
    for (int c = 0; c < 8; ++c) {
        const float w = wx[(c >> 2) & 1] * wy[(c >> 1) & 1] * wz[c & 1];
        acc.x = fmaf(w, e[c].x, acc.x);
        acc.y = fmaf(w, e[c].y, acc.y);
        acc.z = fmaf(w, e[c].z, acc.z);
        acc.w = fmaf(w, e[c].w, acc.w);
    }

    __builtin_nontemporal_store(acc, (v4f*)(out + 16 * (size_t)orig + 4 * q));
}

// ---------------- fallback (no-sort direct), used only if ws too small ----------------
__global__ __launch_bounds__(256) void k_direct(
    const float* __restrict__ pts, const int* __restrict__ p2v,
    const float* __restrict__ emb, const float* __restrict__ cp,
    const int* __restrict__ c2c, const float* __restrict__ vox,
    float* __restrict__ out, int N)
{
    const int t = blockIdx.x * blockDim.x + threadIdx.x;
    const int n = t >> 2, q = t & 3;
    if (n >= N) return;
    const int v = p2v[n];
    const int4* c4 = (const int4*)(c2c + 8 * (size_t)v);
    const int4 ci0 = c4[0], ci1 = c4[1];
    const int cidx[8] = {ci0.x, ci0.y, ci0.z, ci0.w, ci1.x, ci1.y, ci1.z, ci1.w};
    v4f e[8];
    #pragma unroll
    for (int c = 0; c < 8; ++c) e[c] = *(const v4f*)(emb + 16 * (size_t)cidx[c] + 4 * q);
    const float inv_vs = 1.0f / vox[0];
    const float* pp = pts + 3 * (size_t)n;
    const float* cpp = cp + 3 * (size_t)v;
    const float px = (pp[0] - cpp[0]) * inv_vs + 0.5f;
    const float py = (pp[1] - cpp[1]) * inv_vs + 0.5f;
    const float pz = (pp[2] - cpp[2]) * inv_vs + 0.5f;
    const float wx[2] = {1.0f - px, px};
    const float wy[2] = {1.0f - py, py};
    const float wz[2] = {1.0f - pz, pz};
    v4f acc = (v4f)(0.0f);
    #pragma unroll
    for (int c = 0; c < 8; ++c) {
        const float w = wx[(c >> 2) & 1] * wy[(c >> 1) & 1] * wz[c & 1];
        acc.x = fmaf(w, e[c].x, acc.x); acc.y = fmaf(w, e[c].y, acc.y);
        acc.z = fmaf(w, e[c].z, acc.z); acc.w = fmaf(w, e[c].w, acc.w);
    }
    __builtin_nontemporal_store(acc, (v4f*)(out + 4 * (size_t)t));
}

extern "C" void kernel_launch(void* const* d_in, const int* in_sizes, int n_in,
                              void* d_out, int out_size, void* d_ws, size_t ws_size,
                              hipStream_t stream) {
    const float* pts = (const float*)d_in[0];
    const int*   p2v = (const int*)d_in[1];
    const float* emb = (const float*)d_in[2];
    const float* cp  = (const float*)d_in[3];
    const int*   c2c = (const int*)d_in[4];
    const float* vox = (const float*)d_in[5];
    float*       out = (float*)d_out;

    const int N  = in_sizes[1];       // 2,000,000 points
    const int NV = in_sizes[4] / 8;   // 500,000 voxels

    // workspace layout (bytes)
    const size_t MB = 1024u * 1024u;
    const size_t off_hist  = 0;            // NXCD * NV * 4  (16 MB)
    const size_t off_bsums = 16u * MB;     // <=1024 * 4
    const size_t off_rank  = 17u * MB;     // N * 4   (8 MB)
    const size_t off_vsort = 25u * MB;     // N * 4   (8 MB)
    const size_t off_rec   = 33u * MB;     // N * 16  (32 MB)
    const size_t need = off_rec + (size_t)N * 16u;

    if (ws_size < need) {
        const int block = 256;
        const long long threads = 4LL * N;
        k_direct<<<(int)((threads + block - 1) / block), block, 0, stream>>>(
            pts, p2v, emb, cp, c2c, vox, out, N);
        return;
    }

    unsigned* hist  = (unsigned*)((char*)d_ws + off_hist);
    unsigned* bsums = (unsigned*)((char*)d_ws + off_bsums);
    unsigned* rank  = (unsigned*)((char*)d_ws + off_rank);
    unsigned* vsort = (unsigned*)((char*)d_ws + off_vsort);
    v4f*      rec   = (v4f*)((char*)d_ws + off_rec);

    const int block = 256;
    const int nscan = (NV + 1023) / 1024;   // 489 blocks; k_scan_sums handles <=1024
    const int nzero = NXCD * NV;

    k_zero<<<(nzero + block - 1) / block, block, 0, stream>>>(hist, nzero);
    k_hist_rank<<<(N + block * 8 - 1) / (block * 8), block, 0, stream>>>(p2v, hist, rank, N, NV);
    k_scan_blocks<<<nscan, 256, 0, stream>>>(hist, bsums, NV);
    k_scan_sums<<<1, 256, 0, stream>>>(bsums, nscan);
    k_place<<<(N + block * 4 - 1) / (block * 4), block, 0, stream>>>(
        pts, p2v, rank, hist, bsums, vsort, rec, N, NV);

    const long long threads = 4LL * N;
    k_main<<<(int)((threads + block - 1) / block), block, 0, stream>>>(
        vsort, rec, emb, cp, c2c, vox, out, N);
}

// Round 7
// 403.414 us; speedup vs baseline: 1.1967x; 1.1834x over previous
//
#include <hip/hip_runtime.h>

// VoxelEncoding — two-level bucket counting-sort, LDS atomics, then gather-interp.
//
// Measured r0-r6:
//   - 2M returning GLOBAL atomics run at ~13-17 Gop/s regardless of scope
//     (device vs XCD-local) or ILP (x1 vs x8): each is a line-granular RMW at
//     the cache/fabric (64 B/op WRITE_SIZE signature) -> ~120-150 us/pass.
//     Only cure: issue ~8x FEWER global atomics.
//   - scattered 20-B payload writes over 40 MB: ~100-120 us (r4 k_place).
//     Cure: scatter in ~134-B contiguous runs (bucketed), compact per-bucket.
//   - k_main: 127 us @ FETCH 278 MB = 500Kx8x64-B emb-line gather at
//     ~3.2 TB/s L2-miss service = random-line roofline. Done; split in two
//     half dispatches only for profiler visibility of the sort kernels.
//
// Fast path (ws >= ~90 MB):
//   K_init  : gbase[b] = b*CAP
//   K_bucket: per-wg (2048 pts) LDS hist of 245 buckets (v>>11) ->
//             1 global returning atomic per (wg,bucket) (~239K total) ->
//             LDS-atomic append: scatter {x,y,z,orig}(16B)+v(4B) into
//             CAP-strided bucket regions (contiguous per-wg runs)
//   K_scan  : exclusive scan of 245 bucket counts -> bo[]
//   K_binsort: wg per bucket: LDS 2048-bin hist + LDS scan + LDS-atomic rank;
//             write final rec/vsort contiguously at bo[b] (L2-local window)
//   K_main x2: proven interp kernel over sorted points (halved for profiling)
// Fallback (ws >= 52 MB): r4 pipeline (single global-atomic pass, 458 us).
// Last resort: k_direct.

typedef float v4f __attribute__((ext_vector_type(4)));

// ==================== FAST PATH ====================

__global__ void k_init_gbase(unsigned* __restrict__ gbase, int NB, unsigned CAP) {
    int i = blockIdx.x * blockDim.x + threadIdx.x;
    if (i < NB) gbase[i] = (unsigned)i * CAP;
}

// ---- K_bucket: 2048 pts/wg, LDS bucket hist, coarse scatter ----
__global__ __launch_bounds__(256) void k_bucket(
    const int*   __restrict__ p2v,
    const float* __restrict__ pts,
    unsigned*    __restrict__ gbase,
    unsigned*    __restrict__ vA,
    v4f*         __restrict__ recA,
    int N, int NB)
{
    __shared__ unsigned cnt[512];
    __shared__ unsigned cur[512];
    const int tid = threadIdx.x;
    const int i0 = (blockIdx.x * 256 + tid) * 8;

    for (int b = tid; b < NB; b += 256) cnt[b] = 0u;
    __syncthreads();

    int vv[8];
    const bool full = (i0 + 7 < N);
    if (full) {
        const int4 a = *(const int4*)(p2v + i0);
        const int4 b4 = *(const int4*)(p2v + i0 + 4);
        vv[0]=a.x; vv[1]=a.y; vv[2]=a.z; vv[3]=a.w;
        vv[4]=b4.x; vv[5]=b4.y; vv[6]=b4.z; vv[7]=b4.w;
        #pragma unroll
        for (int k = 0; k < 8; ++k) atomicAdd(&cnt[vv[k] >> 11], 1u);
    } else {
        for (int k = 0; k < 8; ++k)
            if (i0 + k < N) { vv[k] = p2v[i0 + k]; atomicAdd(&cnt[vv[k] >> 11], 1u); }
    }
    __syncthreads();

    // one global returning atomic per (wg, nonempty bucket): ~245/wg
    for (int b = tid; b < NB; b += 256) {
        const unsigned c = cnt[b];
        cur[b] = c ? atomicAdd(&gbase[b], c) : 0u;
    }
    __syncthreads();

    if (full) {
        const v4f* p4 = (const v4f*)pts;
        const size_t fb = (size_t)3 * (size_t)(i0 >> 2);
        const v4f f0 = p4[fb], f1 = p4[fb+1], f2 = p4[fb+2];
        const v4f f3 = p4[fb+3], f4 = p4[fb+4], f5 = p4[fb+5];
        const float xs[8] = {f0.x, f0.w, f1.z, f2.y, f3.x, f3.w, f4.z, f5.y};
        const float ys[8] = {f0.y, f1.x, f1.w, f2.z, f3.y, f4.x, f4.w, f5.z};
        const float zs[8] = {f0.z, f1.y, f2.x, f2.w, f3.z, f4.y, f5.x, f5.w};
        #pragma unroll
        for (int k = 0; k < 8; ++k) {
            const unsigned pos = atomicAdd(&cur[vv[k] >> 11], 1u);
            v4f r; r.x = xs[k]; r.y = ys[k]; r.z = zs[k]; r.w = __int_as_float(i0 + k);
            recA[pos] = r;
            vA[pos] = (unsigned)vv[k];
        }
    } else {
        for (int k = 0; k < 8; ++k) {
            const int i = i0 + k;
            if (i >= N) break;
            const unsigned pos = atomicAdd(&cur[vv[k] >> 11], 1u);
            v4f r;
            r.x = pts[3*(size_t)i]; r.y = pts[3*(size_t)i+1]; r.z = pts[3*(size_t)i+2];
            r.w = __int_as_float(i);
            recA[pos] = r;
            vA[pos] = (unsigned)vv[k];
        }
    }
}

// ---- K_scan: exclusive scan of bucket counts (NB <= 512), single wg ----
__global__ __launch_bounds__(256) void k_scan_nb(const unsigned* __restrict__ gbase,
                                                 unsigned* __restrict__ bo,
                                                 int NB, unsigned CAP) {
    __shared__ unsigned tsum[256];
    const int tid = threadIdx.x;
    const int i0 = tid * 2;
    const unsigned c0 = (i0     < NB) ? gbase[i0]     - (unsigned)i0       * CAP : 0u;
    const unsigned c1 = (i0 + 1 < NB) ? gbase[i0 + 1] - (unsigned)(i0 + 1) * CAP : 0u;
    tsum[tid] = c0 + c1; __syncthreads();
    for (int off = 1; off < 256; off <<= 1) {
        unsigned x = tsum[tid];
        unsigned y = (tid >= off) ? tsum[tid - off] : 0u;
        __syncthreads();
        tsum[tid] = x + y;
        __syncthreads();
    }
    const unsigned prefix = (tid > 0) ? tsum[tid - 1] : 0u;
    if (i0     < NB) bo[i0]     = prefix;
    if (i0 + 1 < NB) bo[i0 + 1] = prefix + c0;
}

// ---- K_binsort: one wg per bucket, 2048-bin LDS sort, compact to final ----
__global__ __launch_bounds__(256) void k_binsort(
    const unsigned* __restrict__ gbase,
    const unsigned* __restrict__ bo,
    const unsigned* __restrict__ vA,
    const v4f*      __restrict__ recA,
    unsigned*       __restrict__ vsort,
    v4f*            __restrict__ rec,
    unsigned CAP)
{
    __shared__ unsigned h[2048];
    __shared__ unsigned tsum[256];
    const int b   = blockIdx.x;
    const int tid = threadIdx.x;
    const unsigned in0   = (unsigned)b * CAP;
    const unsigned cntb  = gbase[b] - in0;
    const unsigned obase = bo[b];
    const unsigned vbase = (unsigned)b << 11;

    #pragma unroll
    for (int k = 0; k < 8; ++k) h[tid + 256 * k] = 0u;
    __syncthreads();

    for (unsigned j = tid; j < cntb; j += 256)
        atomicAdd(&h[vA[in0 + j] - vbase], 1u);
    __syncthreads();

    // exclusive scan of h[2048]: 8 serial per thread + block scan
    unsigned loc[8]; unsigned s = 0;
    #pragma unroll
    for (int k = 0; k < 8; ++k) { loc[k] = s; s += h[tid * 8 + k]; }
    tsum[tid] = s; __syncthreads();
    for (int off = 1; off < 256; off <<= 1) {
        unsigned x = tsum[tid];
        unsigned y = (tid >= off) ? tsum[tid - off] : 0u;
        __syncthreads();
        tsum[tid] = x + y;
        __syncthreads();
    }
    const unsigned pre = (tid > 0) ? tsum[tid - 1] : 0u;
    #pragma unroll
    for (int k = 0; k < 8; ++k) h[tid * 8 + k] = pre + loc[k];
    __syncthreads();

    for (unsigned j = tid; j < cntb; j += 256) {
        const unsigned v = vA[in0 + j];
        const unsigned r = atomicAdd(&h[v - vbase], 1u);
        const unsigned pos = obase + r;
        vsort[pos] = v;
        rec[pos] = recA[in0 + j];
    }
}

// ---- K_main: interpolation over sorted points [n0, n1) ----
__global__ __launch_bounds__(256) void k_main(
    const unsigned* __restrict__ vsort, const v4f* __restrict__ rec,
    const float* __restrict__ emb,   // (N_EMB,16)
    const float* __restrict__ cp,    // (N_VOX,3)
    const int*   __restrict__ c2c,   // (N_VOX,8)
    const float* __restrict__ vox,
    float*       __restrict__ out,   // (N,16)
    int n0, int n1)
{
    const int t = blockIdx.x * blockDim.x + threadIdx.x;
    const int n = n0 + (t >> 2);
    const int q = t & 3;
    if (n >= n1) return;

    const unsigned v = vsort[n];
    const v4f r = rec[n];
    const int orig = __float_as_int(r.w);

    const int4* c4 = (const int4*)(c2c + 8 * (size_t)v);
    const int4 ci0 = c4[0];
    const int4 ci1 = c4[1];
    const int cidx[8] = {ci0.x, ci0.y, ci0.z, ci0.w, ci1.x, ci1.y, ci1.z, ci1.w};

    v4f e[8];
    #pragma unroll
    for (int c = 0; c < 8; ++c) {
        e[c] = *(const v4f*)(emb + 16 * (size_t)cidx[c] + 4 * q);
    }

    const float inv_vs = 1.0f / vox[0];
    const float* cpp = cp + 3 * (size_t)v;
    const float px = (r.x - cpp[0]) * inv_vs + 0.5f;
    const float py = (r.y - cpp[1]) * inv_vs + 0.5f;
    const float pz = (r.z - cpp[2]) * inv_vs + 0.5f;
    const float wx[2] = {1.0f - px, px};
    const float wy[2] = {1.0f - py, py};
    const float wz[2] = {1.0f - pz, pz};

    v4f acc = (v4f)(0.0f);
    #pragma unroll
    for (int c = 0; c < 8; ++c) {
        const float w = wx[(c >> 2) & 1] * wy[(c >> 1) & 1] * wz[c & 1];
        acc.x = fmaf(w, e[c].x, acc.x);
        acc.y = fmaf(w, e[c].y, acc.y);
        acc.z = fmaf(w, e[c].z, acc.z);
        acc.w = fmaf(w, e[c].w, acc.w);
    }

    __builtin_nontemporal_store(acc, (v4f*)(out + 16 * (size_t)orig + 4 * q));
}

// ==================== FALLBACK PATH (r4, 52 MB ws) ====================

__global__ void k_zero(unsigned* __restrict__ hist, int n) {
    int i = blockIdx.x * blockDim.x + threadIdx.x;
    if (i < n) hist[i] = 0u;
}

__global__ __launch_bounds__(256) void k_hist_rank(const int* __restrict__ p2v,
                                                   unsigned* __restrict__ hist,
                                                   unsigned* __restrict__ rank, int N) {
    const int base = (blockIdx.x * blockDim.x + threadIdx.x) * 8;
    if (base + 7 < N) {
        const int4 a = *(const int4*)(p2v + base);
        const int4 b = *(const int4*)(p2v + base + 4);
        const unsigned r0 = atomicAdd(&hist[a.x], 1u);
        const unsigned r1 = atomicAdd(&hist[a.y], 1u);
        const unsigned r2 = atomicAdd(&hist[a.z], 1u);
        const unsigned r3 = atomicAdd(&hist[a.w], 1u);
        const unsigned r4 = atomicAdd(&hist[b.x], 1u);
        const unsigned r5 = atomicAdd(&hist[b.y], 1u);
        const unsigned r6 = atomicAdd(&hist[b.z], 1u);
        const unsigned r7 = atomicAdd(&hist[b.w], 1u);
        uint4 o0; o0.x = r0; o0.y = r1; o0.z = r2; o0.w = r3;
        uint4 o1; o1.x = r4; o1.y = r5; o1.z = r6; o1.w = r7;
        *(uint4*)(rank + base)     = o0;
        *(uint4*)(rank + base + 4) = o1;
    } else {
        for (int k = 0; k < 8; ++k)
            if (base + k < N) rank[base + k] = atomicAdd(&hist[p2v[base + k]], 1u);
    }
}

__global__ __launch_bounds__(256) void k_scan_blocks(unsigned* __restrict__ hist,
                                                     unsigned* __restrict__ bsums, int nbins) {
    __shared__ unsigned tsum[256];
    const int tid = threadIdx.x;
    const int i0 = blockIdx.x * 1024 + tid * 4;
    unsigned v[4]; unsigned s = 0;
    #pragma unroll
    for (int k = 0; k < 4; ++k) {
        unsigned c = (i0 + k < nbins) ? hist[i0 + k] : 0u;
        v[k] = s; s += c;
    }
    tsum[tid] = s; __syncthreads();
    for (int off = 1; off < 256; off <<= 1) {
        unsigned x = tsum[tid];
        unsigned y = (tid >= off) ? tsum[tid - off] : 0u;
        __syncthreads();
        tsum[tid] = x + y;
        __syncthreads();
    }
    unsigned prefix = (tid > 0) ? tsum[tid - 1] : 0u;
    #pragma unroll
    for (int k = 0; k < 4; ++k) {
        if (i0 + k < nbins) hist[i0 + k] = prefix + v[k];
    }
    if (tid == 255) bsums[blockIdx.x] = tsum[255];
}

__global__ __launch_bounds__(256) void k_scan_sums(unsigned* __restrict__ bsums, int nb) {
    __shared__ unsigned tsum[256];
    const int tid = threadIdx.x;
    const int i0 = tid * 4;
    unsigned v[4]; unsigned s = 0;
    #pragma unroll
    for (int k = 0; k < 4; ++k) {
        unsigned c = (i0 + k < nb) ? bsums[i0 + k] : 0u;
        v[k] = s; s += c;
    }
    tsum[tid] = s; __syncthreads();
    for (int off = 1; off < 256; off <<= 1) {
        unsigned x = tsum[tid];
        unsigned y = (tid >= off) ? tsum[tid - off] : 0u;
        __syncthreads();
        tsum[tid] = x + y;
        __syncthreads();
    }
    unsigned prefix = (tid > 0) ? tsum[tid - 1] : 0u;
    #pragma unroll
    for (int k = 0; k < 4; ++k) {
        if (i0 + k < nb) bsums[i0 + k] = prefix + v[k];
    }
}

__global__ __launch_bounds__(256) void k_place(
    const float* __restrict__ pts,
    const int*   __restrict__ p2v,
    const unsigned* __restrict__ rank,
    const unsigned* __restrict__ hist,
    const unsigned* __restrict__ bsums,
    unsigned* __restrict__ vsort,
    v4f*      __restrict__ rec,
    int N)
{
    const int base = (blockIdx.x * blockDim.x + threadIdx.x) * 4;
    if (base + 3 < N) {
        const int4  v4r = *(const int4*)(p2v + base);
        const uint4 r4  = *(const uint4*)(rank + base);
        const v4f* p4 = (const v4f*)pts;
        const size_t f0i = (size_t)(3 * (base >> 2));
        const v4f f0 = p4[f0i];
        const v4f f1 = p4[f0i + 1];
        const v4f f2 = p4[f0i + 2];

        const unsigned pos0 = hist[v4r.x] + bsums[((unsigned)v4r.x) >> 10] + r4.x;
        const unsigned pos1 = hist[v4r.y] + bsums[((unsigned)v4r.y) >> 10] + r4.y;
        const unsigned pos2 = hist[v4r.z] + bsums[((unsigned)v4r.z) >> 10] + r4.z;
        const unsigned pos3 = hist[v4r.w] + bsums[((unsigned)v4r.w) >> 10] + r4.w;

        vsort[pos0] = (unsigned)v4r.x;
        vsort[pos1] = (unsigned)v4r.y;
        vsort[pos2] = (unsigned)v4r.z;
        vsort[pos3] = (unsigned)v4r.w;

        v4f a;
        a.x = f0.x; a.y = f0.y; a.z = f0.z; a.w = __int_as_float(base + 0);
        rec[pos0] = a;
        a.x = f0.w; a.y = f1.x; a.z = f1.y; a.w = __int_as_float(base + 1);
        rec[pos1] = a;
        a.x = f1.z; a.y = f1.w; a.z = f2.x; a.w = __int_as_float(base + 2);
        rec[pos2] = a;
        a.x = f2.y; a.y = f2.z; a.z = f2.w; a.w = __int_as_float(base + 3);
        rec[pos3] = a;
    } else {
        for (int k = 0; k < 4; ++k) {
            const int i = base + k;
            if (i >= N) break;
            const int v = p2v[i];
            const unsigned pos = hist[v] + bsums[((unsigned)v) >> 10] + rank[i];
            vsort[pos] = (unsigned)v;
            v4f r;
            r.x = pts[3 * (size_t)i + 0];
            r.y = pts[3 * (size_t)i + 1];
            r.z = pts[3 * (size_t)i + 2];
            r.w = __int_as_float(i);
            rec[pos] = r;
        }
    }
}

__global__ __launch_bounds__(256) void k_direct(
    const float* __restrict__ pts, const int* __restrict__ p2v,
    const float* __restrict__ emb, const float* __restrict__ cp,
    const int* __restrict__ c2c, const float* __restrict__ vox,
    float* __restrict__ out, int N)
{
    const int t = blockIdx.x * blockDim.x + threadIdx.x;
    const int n = t >> 2, q = t & 3;
    if (n >= N) return;
    const int v = p2v[n];
    const int4* c4 = (const int4*)(c2c + 8 * (size_t)v);
    const int4 ci0 = c4[0], ci1 = c4[1];
    const int cidx[8] = {ci0.x, ci0.y, ci0.z, ci0.w, ci1.x, ci1.y, ci1.z, ci1.w};
    v4f e[8];
    #pragma unroll
    for (int c = 0; c < 8; ++c) e[c] = *(const v4f*)(emb + 16 * (size_t)cidx[c] + 4 * q);
    const float inv_vs = 1.0f / vox[0];
    const float* pp = pts + 3 * (size_t)n;
    const float* cpp = cp + 3 * (size_t)v;
    const float px = (pp[0] - cpp[0]) * inv_vs + 0.5f;
    const float py = (pp[1] - cpp[1]) * inv_vs + 0.5f;
    const float pz = (pp[2] - cpp[2]) * inv_vs + 0.5f;
    const float wx[2] = {1.0f - px, px};
    const float wy[2] = {1.0f - py, py};
    const float wz[2] = {1.0f - pz, pz};
    v4f acc = (v4f)(0.0f);
    #pragma unroll
    for (int c = 0; c < 8; ++c) {
        const float w = wx[(c >> 2) & 1] * wy[(c >> 1) & 1] * wz[c & 1];
        acc.x = fmaf(w, e[c].x, acc.x); acc.y = fmaf(w, e[c].y, acc.y);
        acc.z = fmaf(w, e[c].z, acc.z); acc.w = fmaf(w, e[c].w, acc.w);
    }
    __builtin_nontemporal_store(acc, (v4f*)(out + 4 * (size_t)t));
}

// ==================== LAUNCHER ====================

extern "C" void kernel_launch(void* const* d_in, const int* in_sizes, int n_in,
                              void* d_out, int out_size, void* d_ws, size_t ws_size,
                              hipStream_t stream) {
    const float* pts = (const float*)d_in[0];
    const int*   p2v = (const int*)d_in[1];
    const float* emb = (const float*)d_in[2];
    const float* cp  = (const float*)d_in[3];
    const int*   c2c = (const int*)d_in[4];
    const float* vox = (const float*)d_in[5];
    float*       out = (float*)d_out;

    const int N  = in_sizes[1];       // 2,000,000 points
    const int NV = in_sizes[4] / 8;   // 500,000 voxels
    const int block = 256;

    // ---------- fast path: two-level bucket sort ----------
    const int NB = (NV + 2047) >> 11;                 // buckets of 2048 bins
    if (NB >= 1 && NB <= 512) {
        const unsigned CAP = (unsigned)(N / NB) + 2048u;   // mean + ~22 sigma
        const size_t off_gbase = 0;                         // 512*4
        const size_t off_bo    = 4096;                      // 512*4
        const size_t off_vA    = 8192;
        const size_t sz_vA     = (size_t)NB * CAP * 4u;
        const size_t off_recA  = (off_vA + sz_vA + 255u) & ~(size_t)255u;
        const size_t sz_recA   = (size_t)NB * CAP * 16u;
        const size_t off_vsF   = (off_recA + sz_recA + 255u) & ~(size_t)255u;
        const size_t off_recF  = (off_vsF + (size_t)N * 4u + 255u) & ~(size_t)255u;
        const size_t need_fast = off_recF + (size_t)N * 16u;

        if (ws_size >= need_fast) {
            unsigned* gbase = (unsigned*)((char*)d_ws + off_gbase);
            unsigned* bo    = (unsigned*)((char*)d_ws + off_bo);
            unsigned* vA    = (unsigned*)((char*)d_ws + off_vA);
            v4f*      recA  = (v4f*)((char*)d_ws + off_recA);
            unsigned* vsort = (unsigned*)((char*)d_ws + off_vsF);
            v4f*      rec   = (v4f*)((char*)d_ws + off_recF);

            k_init_gbase<<<(NB + block - 1) / block, block, 0, stream>>>(gbase, NB, CAP);
            k_bucket<<<(N + 2047) / 2048, block, 0, stream>>>(p2v, pts, gbase, vA, recA, N, NB);
            k_scan_nb<<<1, block, 0, stream>>>(gbase, bo, NB, CAP);
            k_binsort<<<NB, block, 0, stream>>>(gbase, bo, vA, recA, vsort, rec, CAP);

            const int half = N / 2;
            const long long th0 = 4LL * half;
            const long long th1 = 4LL * (N - half);
            k_main<<<(int)((th0 + block - 1) / block), block, 0, stream>>>(
                vsort, rec, emb, cp, c2c, vox, out, 0, half);
            k_main<<<(int)((th1 + block - 1) / block), block, 0, stream>>>(
                vsort, rec, emb, cp, c2c, vox, out, half, N);
            return;
        }
    }

    // ---------- fallback: r4 pipeline (52 MB ws) ----------
    {
        const size_t MB = 1024u * 1024u;
        const size_t off_hist  = 0;                 // NV*4 (2 MB)
        const size_t off_bsums = 2u * MB;
        const size_t off_rank  = 4u * MB;           // N*4 (8 MB)
        const size_t off_vsort = 12u * MB;          // N*4 (8 MB)
        const size_t off_rec   = 20u * MB;          // N*16 (32 MB)
        const size_t need = off_rec + (size_t)N * 16u;

        if (ws_size >= need) {
            unsigned* hist  = (unsigned*)((char*)d_ws + off_hist);
            unsigned* bsums = (unsigned*)((char*)d_ws + off_bsums);
            unsigned* rank  = (unsigned*)((char*)d_ws + off_rank);
            unsigned* vsort = (unsigned*)((char*)d_ws + off_vsort);
            v4f*      rec   = (v4f*)((char*)d_ws + off_rec);

            const int nscan = (NV + 1023) / 1024;

            k_zero<<<(NV + block - 1) / block, block, 0, stream>>>(hist, NV);
            k_hist_rank<<<(N + block * 8 - 1) / (block * 8), block, 0, stream>>>(p2v, hist, rank, N);
            k_scan_blocks<<<nscan, 256, 0, stream>>>(hist, bsums, NV);
            k_scan_sums<<<1, 256, 0, stream>>>(bsums, nscan);
            k_place<<<(N + block * 4 - 1) / (block * 4), block, 0, stream>>>(
                pts, p2v, rank, hist, bsums, vsort, rec, N);

            const long long threads = 4LL * N;
            k_main<<<(int)((threads + block - 1) / block), block, 0, stream>>>(
                vsort, rec, emb, cp, c2c, vox, out, 0, N);
            return;
        }
    }

    // ---------- last resort ----------
    {
        const long long threads = 4LL * N;
        k_direct<<<(int)((threads + block - 1) / block), block, 0, stream>>>(
            pts, p2v, emb, cp, c2c, vox, out, N);
    }
}

// Round 8
// 383.427 us; speedup vs baseline: 1.2591x; 1.0521x over previous
//
#include <hip/hip_runtime.h>

// VoxelEncoding — two-level bucket counting-sort (LDS atomics) + gather-interp.
//
// Measured r0-r7:
//   - 2M returning GLOBAL atomics: ~13-17 Gop/s wall regardless of scope/ILP
//     (line-granular RMW at the fabric). Bucketing cut this to ~60-240K ops.
//   - k_main: 127 us @ FETCH 278 MB = sorted-order 8-corner emb-line gather
//     at ~3.2 TB/s = random-line roofline. Done.
//   - Harness re-poison fill (512 MB, ~80 us) sits inside the timed window
//     every iteration — fixed floor, not controllable from kernel code.
//   - r7 residual ~195 us was the sort side: k_binsort at 245 wgs x 4 waves
//     = 12% occupancy, 32-deep dependent loop. Fix: 1024-thread blocks
//     (48% occupancy, 8 iters) for both binsort and bucket; bucket gets
//     60K atomics (245x245) and ~530-B contiguous runs (amp ~1.1x).
//
// Fast path (ws >= ~90 MB):
//   K_init   : gbase[b] = b*CAP
//   K_bucket : 8192 pts/wg (1024 thr): LDS hist of 245 buckets (v>>11) ->
//              1 returning atomic per (wg,bucket) -> LDS-atomic append into
//              CAP-strided bucket regions ({x,y,z,orig} 16B + v 4B)
//   K_scan_nb: exclusive scan of 245 bucket counts
//   K_binsort: wg (1024 thr) per bucket: LDS 2048-bin hist + scan + rank;
//              compact rec/vsort contiguously at bo[b] (L2-local window)
//   K_main   : proven interp kernel over sorted points (single dispatch)
// Fallback (ws >= 52 MB): r4 pipeline. Last resort: k_direct.

typedef float v4f __attribute__((ext_vector_type(4)));

// ==================== FAST PATH ====================

__global__ void k_init_gbase(unsigned* __restrict__ gbase, int NB, unsigned CAP) {
    int i = blockIdx.x * blockDim.x + threadIdx.x;
    if (i < NB) gbase[i] = (unsigned)i * CAP;
}

// ---- K_bucket: 8192 pts/wg (1024 thr, 8/thread), LDS bucket hist, coarse scatter ----
__global__ __launch_bounds__(1024) void k_bucket(
    const int*   __restrict__ p2v,
    const float* __restrict__ pts,
    unsigned*    __restrict__ gbase,
    unsigned*    __restrict__ vA,
    v4f*         __restrict__ recA,
    int N, int NB)
{
    __shared__ unsigned cnt[512];
    __shared__ unsigned cur[512];
    const int tid = threadIdx.x;
    const int i0 = (blockIdx.x * 1024 + tid) * 8;

    for (int b = tid; b < NB; b += 1024) cnt[b] = 0u;
    __syncthreads();

    int vv[8];
    const bool full = (i0 + 7 < N);
    if (full) {
        const int4 a = *(const int4*)(p2v + i0);
        const int4 b4 = *(const int4*)(p2v + i0 + 4);
        vv[0]=a.x; vv[1]=a.y; vv[2]=a.z; vv[3]=a.w;
        vv[4]=b4.x; vv[5]=b4.y; vv[6]=b4.z; vv[7]=b4.w;
        #pragma unroll
        for (int k = 0; k < 8; ++k) atomicAdd(&cnt[vv[k] >> 11], 1u);
    } else {
        for (int k = 0; k < 8; ++k)
            if (i0 + k < N) { vv[k] = p2v[i0 + k]; atomicAdd(&cnt[vv[k] >> 11], 1u); }
    }
    __syncthreads();

    // one global returning atomic per (wg, nonempty bucket): ~245/wg, 245 wgs
    for (int b = tid; b < NB; b += 1024) {
        const unsigned c = cnt[b];
        cur[b] = c ? atomicAdd(&gbase[b], c) : 0u;
    }
    __syncthreads();

    if (full) {
        const v4f* p4 = (const v4f*)pts;
        const size_t fb = (size_t)3 * (size_t)(i0 >> 2);
        const v4f f0 = p4[fb], f1 = p4[fb+1], f2 = p4[fb+2];
        const v4f f3 = p4[fb+3], f4 = p4[fb+4], f5 = p4[fb+5];
        const float xs[8] = {f0.x, f0.w, f1.z, f2.y, f3.x, f3.w, f4.z, f5.y};
        const float ys[8] = {f0.y, f1.x, f1.w, f2.z, f3.y, f4.x, f4.w, f5.z};
        const float zs[8] = {f0.z, f1.y, f2.x, f2.w, f3.z, f4.y, f5.x, f5.w};
        #pragma unroll
        for (int k = 0; k < 8; ++k) {
            const unsigned pos = atomicAdd(&cur[vv[k] >> 11], 1u);
            v4f r; r.x = xs[k]; r.y = ys[k]; r.z = zs[k]; r.w = __int_as_float(i0 + k);
            recA[pos] = r;
            vA[pos] = (unsigned)vv[k];
        }
    } else {
        for (int k = 0; k < 8; ++k) {
            const int i = i0 + k;
            if (i >= N) break;
            const unsigned pos = atomicAdd(&cur[vv[k] >> 11], 1u);
            v4f r;
            r.x = pts[3*(size_t)i]; r.y = pts[3*(size_t)i+1]; r.z = pts[3*(size_t)i+2];
            r.w = __int_as_float(i);
            recA[pos] = r;
            vA[pos] = (unsigned)vv[k];
        }
    }
}

// ---- K_scan: exclusive scan of bucket counts (NB <= 512), single wg ----
__global__ __launch_bounds__(256) void k_scan_nb(const unsigned* __restrict__ gbase,
                                                 unsigned* __restrict__ bo,
                                                 int NB, unsigned CAP) {
    __shared__ unsigned tsum[256];
    const int tid = threadIdx.x;
    const int i0 = tid * 2;
    const unsigned c0 = (i0     < NB) ? gbase[i0]     - (unsigned)i0       * CAP : 0u;
    const unsigned c1 = (i0 + 1 < NB) ? gbase[i0 + 1] - (unsigned)(i0 + 1) * CAP : 0u;
    tsum[tid] = c0 + c1; __syncthreads();
    for (int off = 1; off < 256; off <<= 1) {
        unsigned x = tsum[tid];
        unsigned y = (tid >= off) ? tsum[tid - off] : 0u;
        __syncthreads();
        tsum[tid] = x + y;
        __syncthreads();
    }
    const unsigned prefix = (tid > 0) ? tsum[tid - 1] : 0u;
    if (i0     < NB) bo[i0]     = prefix;
    if (i0 + 1 < NB) bo[i0 + 1] = prefix + c0;
}

// ---- K_binsort: one 1024-thr wg per bucket, 2048-bin LDS sort, compact ----
__global__ __launch_bounds__(1024) void k_binsort(
    const unsigned* __restrict__ gbase,
    const unsigned* __restrict__ bo,
    const unsigned* __restrict__ vA,
    const v4f*      __restrict__ recA,
    unsigned*       __restrict__ vsort,
    v4f*            __restrict__ rec,
    unsigned CAP)
{
    __shared__ unsigned h[2048];
    __shared__ unsigned tsum[1024];
    const int b   = blockIdx.x;
    const int tid = threadIdx.x;
    const unsigned in0   = (unsigned)b * CAP;
    const unsigned cntb  = gbase[b] - in0;
    const unsigned obase = bo[b];
    const unsigned vbase = (unsigned)b << 11;

    h[tid] = 0u; h[tid + 1024] = 0u;
    __syncthreads();

    for (unsigned j = tid; j < cntb; j += 1024)
        atomicAdd(&h[vA[in0 + j] - vbase], 1u);
    __syncthreads();

    // exclusive scan of h[2048]: 2 bins/thread + block scan of 1024
    const unsigned a0 = h[2 * tid];
    const unsigned a1 = h[2 * tid + 1];
    tsum[tid] = a0 + a1; __syncthreads();
    for (int off = 1; off < 1024; off <<= 1) {
        unsigned x = tsum[tid];
        unsigned y = (tid >= off) ? tsum[tid - off] : 0u;
        __syncthreads();
        tsum[tid] = x + y;
        __syncthreads();
    }
    const unsigned pre = (tid > 0) ? tsum[tid - 1] : 0u;
    h[2 * tid]     = pre;
    h[2 * tid + 1] = pre + a0;
    __syncthreads();

    for (unsigned j = tid; j < cntb; j += 1024) {
        const unsigned v = vA[in0 + j];
        const unsigned r = atomicAdd(&h[v - vbase], 1u);
        const unsigned pos = obase + r;
        vsort[pos] = v;
        rec[pos] = recA[in0 + j];
    }
}

// ---- K_main: interpolation over sorted points [n0, n1) ----
__global__ __launch_bounds__(256) void k_main(
    const unsigned* __restrict__ vsort, const v4f* __restrict__ rec,
    const float* __restrict__ emb,   // (N_EMB,16)
    const float* __restrict__ cp,    // (N_VOX,3)
    const int*   __restrict__ c2c,   // (N_VOX,8)
    const float* __restrict__ vox,
    float*       __restrict__ out,   // (N,16)
    int n0, int n1)
{
    const int t = blockIdx.x * blockDim.x + threadIdx.x;
    const int n = n0 + (t >> 2);
    const int q = t & 3;
    if (n >= n1) return;

    const unsigned v = vsort[n];
    const v4f r = rec[n];
    const int orig = __float_as_int(r.w);

    const int4* c4 = (const int4*)(c2c + 8 * (size_t)v);
    const int4 ci0 = c4[0];
    const int4 ci1 = c4[1];
    const int cidx[8] = {ci0.x, ci0.y, ci0.z, ci0.w, ci1.x, ci1.y, ci1.z, ci1.w};

    v4f e[8];
    #pragma unroll
    for (int c = 0; c < 8; ++c) {
        e[c] = *(const v4f*)(emb + 16 * (size_t)cidx[c] + 4 * q);
    }

    const float inv_vs = 1.0f / vox[0];
    const float* cpp = cp + 3 * (size_t)v;
    const float px = (r.x - cpp[0]) * inv_vs + 0.5f;
    const float py = (r.y - cpp[1]) * inv_vs + 0.5f;
    const float pz = (r.z - cpp[2]) * inv_vs + 0.5f;
    const float wx[2] = {1.0f - px, px};
    const float wy[2] = {1.0f - py, py};
    const float wz[2] = {1.0f - pz, pz};

    v4f acc = (v4f)(0.0f);
    #pragma unroll
    for (int c = 0; c < 8; ++c) {
        const float w = wx[(c >> 2) & 1] * wy[(c >> 1) & 1] * wz[c & 1];
        acc.x = fmaf(w, e[c].x, acc.x);
        acc.y = fmaf(w, e[c].y, acc.y);
        acc.z = fmaf(w, e[c].z, acc.z);
        acc.w = fmaf(w, e[c].w, acc.w);
    }

    __builtin_nontemporal_store(acc, (v4f*)(out + 16 * (size_t)orig + 4 * q));
}

// ==================== FALLBACK PATH (r4, 52 MB ws) ====================

__global__ void k_zero(unsigned* __restrict__ hist, int n) {
    int i = blockIdx.x * blockDim.x + threadIdx.x;
    if (i < n) hist[i] = 0u;
}

__global__ __launch_bounds__(256) void k_hist_rank(const int* __restrict__ p2v,
                                                   unsigned* __restrict__ hist,
                                                   unsigned* __restrict__ rank, int N) {
    const int base = (blockIdx.x * blockDim.x + threadIdx.x) * 8;
    if (base + 7 < N) {
        const int4 a = *(const int4*)(p2v + base);
        const int4 b = *(const int4*)(p2v + base + 4);
        const unsigned r0 = atomicAdd(&hist[a.x], 1u);
        const unsigned r1 = atomicAdd(&hist[a.y], 1u);
        const unsigned r2 = atomicAdd(&hist[a.z], 1u);
        const unsigned r3 = atomicAdd(&hist[a.w], 1u);
        const unsigned r4 = atomicAdd(&hist[b.x], 1u);
        const unsigned r5 = atomicAdd(&hist[b.y], 1u);
        const unsigned r6 = atomicAdd(&hist[b.z], 1u);
        const unsigned r7 = atomicAdd(&hist[b.w], 1u);
        uint4 o0; o0.x = r0; o0.y = r1; o0.z = r2; o0.w = r3;
        uint4 o1; o1.x = r4; o1.y = r5; o1.z = r6; o1.w = r7;
        *(uint4*)(rank + base)     = o0;
        *(uint4*)(rank + base + 4) = o1;
    } else {
        for (int k = 0; k < 8; ++k)
            if (base + k < N) rank[base + k] = atomicAdd(&hist[p2v[base + k]], 1u);
    }
}

__global__ __launch_bounds__(256) void k_scan_blocks(unsigned* __restrict__ hist,
                                                     unsigned* __restrict__ bsums, int nbins) {
    __shared__ unsigned tsum[256];
    const int tid = threadIdx.x;
    const int i0 = blockIdx.x * 1024 + tid * 4;
    unsigned v[4]; unsigned s = 0;
    #pragma unroll
    for (int k = 0; k < 4; ++k) {
        unsigned c = (i0 + k < nbins) ? hist[i0 + k] : 0u;
        v[k] = s; s += c;
    }
    tsum[tid] = s; __syncthreads();
    for (int off = 1; off < 256; off <<= 1) {
        unsigned x = tsum[tid];
        unsigned y = (tid >= off) ? tsum[tid - off] : 0u;
        __syncthreads();
        tsum[tid] = x + y;
        __syncthreads();
    }
    unsigned prefix = (tid > 0) ? tsum[tid - 1] : 0u;
    #pragma unroll
    for (int k = 0; k < 4; ++k) {
        if (i0 + k < nbins) hist[i0 + k] = prefix + v[k];
    }
    if (tid == 255) bsums[blockIdx.x] = tsum[255];
}

__global__ __launch_bounds__(256) void k_scan_sums(unsigned* __restrict__ bsums, int nb) {
    __shared__ unsigned tsum[256];
    const int tid = threadIdx.x;
    const int i0 = tid * 4;
    unsigned v[4]; unsigned s = 0;
    #pragma unroll
    for (int k = 0; k < 4; ++k) {
        unsigned c = (i0 + k < nb) ? bsums[i0 + k] : 0u;
        v[k] = s; s += c;
    }
    tsum[tid] = s; __syncthreads();
    for (int off = 1; off < 256; off <<= 1) {
        unsigned x = tsum[tid];
        unsigned y = (tid >= off) ? tsum[tid - off] : 0u;
        __syncthreads();
        tsum[tid] = x + y;
        __syncthreads();
    }
    unsigned prefix = (tid > 0) ? tsum[tid - 1] : 0u;
    #pragma unroll
    for (int k = 0; k < 4; ++k) {
        if (i0 + k < nb) bsums[i0 + k] = prefix + v[k];
    }
}

__global__ __launch_bounds__(256) void k_place(
    const float* __restrict__ pts,
    const int*   __restrict__ p2v,
    const unsigned* __restrict__ rank,
    const unsigned* __restrict__ hist,
    const unsigned* __restrict__ bsums,
    unsigned* __restrict__ vsort,
    v4f*      __restrict__ rec,
    int N)
{
    const int base = (blockIdx.x * blockDim.x + threadIdx.x) * 4;
    if (base + 3 < N) {
        const int4  v4r = *(const int4*)(p2v + base);
        const uint4 r4  = *(const uint4*)(rank + base);
        const v4f* p4 = (const v4f*)pts;
        const size_t f0i = (size_t)(3 * (base >> 2));
        const v4f f0 = p4[f0i];
        const v4f f1 = p4[f0i + 1];
        const v4f f2 = p4[f0i + 2];

        const unsigned pos0 = hist[v4r.x] + bsums[((unsigned)v4r.x) >> 10] + r4.x;
        const unsigned pos1 = hist[v4r.y] + bsums[((unsigned)v4r.y) >> 10] + r4.y;
        const unsigned pos2 = hist[v4r.z] + bsums[((unsigned)v4r.z) >> 10] + r4.z;
        const unsigned pos3 = hist[v4r.w] + bsums[((unsigned)v4r.w) >> 10] + r4.w;

        vsort[pos0] = (unsigned)v4r.x;
        vsort[pos1] = (unsigned)v4r.y;
        vsort[pos2] = (unsigned)v4r.z;
        vsort[pos3] = (unsigned)v4r.w;

        v4f a;
        a.x = f0.x; a.y = f0.y; a.z = f0.z; a.w = __int_as_float(base + 0);
        rec[pos0] = a;
        a.x = f0.w; a.y = f1.x; a.z = f1.y; a.w = __int_as_float(base + 1);
        rec[pos1] = a;
        a.x = f1.z; a.y = f1.w; a.z = f2.x; a.w = __int_as_float(base + 2);
        rec[pos2] = a;
        a.x = f2.y; a.y = f2.z; a.z = f2.w; a.w = __int_as_float(base + 3);
        rec[pos3] = a;
    } else {
        for (int k = 0; k < 4; ++k) {
            const int i = base + k;
            if (i >= N) break;
            const int v = p2v[i];
            const unsigned pos = hist[v] + bsums[((unsigned)v) >> 10] + rank[i];
            vsort[pos] = (unsigned)v;
            v4f r;
            r.x = pts[3 * (size_t)i + 0];
            r.y = pts[3 * (size_t)i + 1];
            r.z = pts[3 * (size_t)i + 2];
            r.w = __int_as_float(i);
            rec[pos] = r;
        }
    }
}

__global__ __launch_bounds__(256) void k_direct(
    const float* __restrict__ pts, const int* __restrict__ p2v,
    const float* __restrict__ emb, const float* __restrict__ cp,
    const int* __restrict__ c2c, const float* __restrict__ vox,
    float* __restrict__ out, int N)
{
    const int t = blockIdx.x * blockDim.x + threadIdx.x;
    const int n = t >> 2, q = t & 3;
    if (n >= N) return;
    const int v = p2v[n];
    const int4* c4 = (const int4*)(c2c + 8 * (size_t)v);
    const int4 ci0 = c4[0], ci1 = c4[1];
    const int cidx[8] = {ci0.x, ci0.y, ci0.z, ci0.w, ci1.x, ci1.y, ci1.z, ci1.w};
    v4f e[8];
    #pragma unroll
    for (int c = 0; c < 8; ++c) e[c] = *(const v4f*)(emb + 16 * (size_t)cidx[c] + 4 * q);
    const float inv_vs = 1.0f / vox[0];
    const float* pp = pts + 3 * (size_t)n;
    const float* cpp = cp + 3 * (size_t)v;
    const float px = (pp[0] - cpp[0]) * inv_vs + 0.5f;
    const float py = (pp[1] - cpp[1]) * inv_vs + 0.5f;
    const float pz = (pp[2] - cpp[2]) * inv_vs + 0.5f;
    const float wx[2] = {1.0f - px, px};
    const float wy[2] = {1.0f - py, py};
    const float wz[2] = {1.0f - pz, pz};
    v4f acc = (v4f)(0.0f);
    #pragma unroll
    for (int c = 0; c < 8; ++c) {
        const float w = wx[(c >> 2) & 1] * wy[(c >> 1) & 1] * wz[c & 1];
        acc.x = fmaf(w, e[c].x, acc.x); acc.y = fmaf(w, e[c].y, acc.y);
        acc.z = fmaf(w, e[c].z, acc.z); acc.w = fmaf(w, e[c].w, acc.w);
    }
    __builtin_nontemporal_store(acc, (v4f*)(out + 4 * (size_t)t));
}

// ==================== LAUNCHER ====================

extern "C" void kernel_launch(void* const* d_in, const int* in_sizes, int n_in,
                              void* d_out, int out_size, void* d_ws, size_t ws_size,
                              hipStream_t stream) {
    const float* pts = (const float*)d_in[0];
    const int*   p2v = (const int*)d_in[1];
    const float* emb = (const float*)d_in[2];
    const float* cp  = (const float*)d_in[3];
    const int*   c2c = (const int*)d_in[4];
    const float* vox = (const float*)d_in[5];
    float*       out = (float*)d_out;

    const int N  = in_sizes[1];       // 2,000,000 points
    const int NV = in_sizes[4] / 8;   // 500,000 voxels
    const int block = 256;

    // ---------- fast path: two-level bucket sort ----------
    const int NB = (NV + 2047) >> 11;                 // buckets of 2048 bins
    if (NB >= 1 && NB <= 512) {
        const unsigned CAP = (unsigned)(N / NB) + 2048u;   // mean + ~22 sigma
        const size_t off_gbase = 0;                         // 512*4
        const size_t off_bo    = 4096;                      // 512*4
        const size_t off_vA    = 8192;
        const size_t sz_vA     = (size_t)NB * CAP * 4u;
        const size_t off_recA  = (off_vA + sz_vA + 255u) & ~(size_t)255u;
        const size_t sz_recA   = (size_t)NB * CAP * 16u;
        const size_t off_vsF   = (off_recA + sz_recA + 255u) & ~(size_t)255u;
        const size_t off_recF  = (off_vsF + (size_t)N * 4u + 255u) & ~(size_t)255u;
        const size_t need_fast = off_recF + (size_t)N * 16u;

        if (ws_size >= need_fast) {
            unsigned* gbase = (unsigned*)((char*)d_ws + off_gbase);
            unsigned* bo    = (unsigned*)((char*)d_ws + off_bo);
            unsigned* vA    = (unsigned*)((char*)d_ws + off_vA);
            v4f*      recA  = (v4f*)((char*)d_ws + off_recA);
            unsigned* vsort = (unsigned*)((char*)d_ws + off_vsF);
            v4f*      rec   = (v4f*)((char*)d_ws + off_recF);

            k_init_gbase<<<(NB + block - 1) / block, block, 0, stream>>>(gbase, NB, CAP);
            k_bucket<<<(N + 8191) / 8192, 1024, 0, stream>>>(p2v, pts, gbase, vA, recA, N, NB);
            k_scan_nb<<<1, block, 0, stream>>>(gbase, bo, NB, CAP);
            k_binsort<<<NB, 1024, 0, stream>>>(gbase, bo, vA, recA, vsort, rec, CAP);

            const long long th = 4LL * N;
            k_main<<<(int)((th + block - 1) / block), block, 0, stream>>>(
                vsort, rec, emb, cp, c2c, vox, out, 0, N);
            return;
        }
    }

    // ---------- fallback: r4 pipeline (52 MB ws) ----------
    {
        const size_t MB = 1024u * 1024u;
        const size_t off_hist  = 0;                 // NV*4 (2 MB)
        const size_t off_bsums = 2u * MB;
        const size_t off_rank  = 4u * MB;           // N*4 (8 MB)
        const size_t off_vsort = 12u * MB;          // N*4 (8 MB)
        const size_t off_rec   = 20u * MB;          // N*16 (32 MB)
        const size_t need = off_rec + (size_t)N * 16u;

        if (ws_size >= need) {
            unsigned* hist  = (unsigned*)((char*)d_ws + off_hist);
            unsigned* bsums = (unsigned*)((char*)d_ws + off_bsums);
            unsigned* rank  = (unsigned*)((char*)d_ws + off_rank);
            unsigned* vsort = (unsigned*)((char*)d_ws + off_vsort);
            v4f*      rec   = (v4f*)((char*)d_ws + off_rec);

            const int nscan = (NV + 1023) / 1024;

            k_zero<<<(NV + block - 1) / block, block, 0, stream>>>(hist, NV);
            k_hist_rank<<<(N + block * 8 - 1) / (block * 8), block, 0, stream>>>(p2v, hist, rank, N);
            k_scan_blocks<<<nscan, 256, 0, stream>>>(hist, bsums, NV);
            k_scan_sums<<<1, 256, 0, stream>>>(bsums, nscan);
            k_place<<<(N + block * 4 - 1) / (block * 4), block, 0, stream>>>(
                pts, p2v, rank, hist, bsums, vsort, rec, N);

            const long long threads = 4LL * N;
            k_main<<<(int)((threads + block - 1) / block), block, 0, stream>>>(
                vsort, rec, emb, cp, c2c, vox, out, 0, N);
            return;
        }
    }

    // ---------- last resort ----------
    {
        const long long threads = 4LL * N;
        k_direct<<<(int)((threads + block - 1) / block), block, 0, stream>>>(
            pts, p2v, emb, cp, c2c, vox, out, N);
    }
}